// Round 4
// baseline (44.801 us; speedup 1.0000x reference)
//
#include <hip/hip_runtime.h>
#include <math.h>

// SH lmax=3 with normalization. f32 (N,3) -> f32 (N,16).
// Coalesced float4 input staging via LDS + LDS-staged coalesced float4 output,
// nontemporal hints on streaming global traffic.

#define TILE 256
#define PAD  17   // 17 floats/edge in LDS out-tile: gcd(17,32)=1 -> conflict-free

typedef float f32x4 __attribute__((ext_vector_type(4)));  // native vector: OK for nontemporal builtins

__global__ __launch_bounds__(256) void sh_lmax3_kernel(
    const float* __restrict__ ev, float* __restrict__ out, int n) {

    __shared__ float si[TILE * 3];    // 3,072 B input stage
    __shared__ float so[TILE * PAD];  // 17,408 B output stage

    const float sqrt3  = 1.7320508075688772f;
    const float sqrt5  = 2.2360679774997896f;
    const float sqrt15 = 3.8729833462074170f;
    const float c30    = 1.0801234497346435f;  // sqrt(42)/6
    const float c31    = 2.6457513110645907f;  // sqrt(7)
    const float c32    = 1.6201851746019651f;  // sqrt(168)/8
    const float c33    = 1.3228756555322954f;  // 0.5*sqrt(7)

    const int t  = threadIdx.x;
    const int e0 = blockIdx.x * TILE;

    // ---- coalesced input stage: tile is TILE*3 floats = TILE*3/4 float4 ----
    const int remaining = n - e0;
    const int nvalid    = remaining >= TILE ? TILE : remaining;
    const int ft        = nvalid * 3;       // floats in this tile
    const int nf4       = ft >> 2;          // full float4s
    const f32x4* iv4    = reinterpret_cast<const f32x4*>(ev + (long long)e0 * 3);

    if (t < nf4) {
        f32x4 v = __builtin_nontemporal_load(&iv4[t]);
        si[4 * t + 0] = v.x;
        si[4 * t + 1] = v.y;
        si[4 * t + 2] = v.z;
        si[4 * t + 3] = v.w;
    }
    if (t == 0) {
        for (int k = nf4 * 4; k < ft; ++k)
            si[k] = ev[(long long)e0 * 3 + k];
    }
    __syncthreads();

    float x = 0.f, y = 0.f, z = 1.f;
    if (t < nvalid) {
        x = si[3 * t + 0];
        y = si[3 * t + 1];
        z = si[3 * t + 2];
    }

    float s  = x * x + y * y + z * z;
    float rn = 1.0f / fmaxf(sqrtf(s), 1e-12f);
    x *= rn; y *= rn; z *= rn;

    float y2   = y * y;
    float x2z2 = x * x + z * z;

    float sh20 = sqrt15 * x * z;
    float sh21 = sqrt15 * x * y;
    float sh22 = sqrt5 * (y2 - 0.5f * x2z2);
    float sh23 = sqrt15 * y * z;
    float sh24 = 0.5f * sqrt15 * (z * z - x * x);

    float sh30 = c30 * (sh20 * z + sh24 * x);
    float sh31 = c31 * sh20 * y;
    float sh32 = c32 * (4.0f * y2 - x2z2) * x;
    float sh33 = c33 * y * (2.0f * y2 - 3.0f * x2z2);
    float sh34 = c32 * z * (4.0f * y2 - x2z2);
    float sh35 = c31 * sh24 * y;
    float sh36 = c30 * (sh24 * z - sh20 * x);

    float* row = &so[t * PAD];
    row[0]  = 1.0f;
    row[1]  = sqrt3 * x;
    row[2]  = sqrt3 * y;
    row[3]  = sqrt3 * z;
    row[4]  = sh20;
    row[5]  = sh21;
    row[6]  = sh22;
    row[7]  = sh23;
    row[8]  = sh24;
    row[9]  = sh30;
    row[10] = sh31;
    row[11] = sh32;
    row[12] = sh33;
    row[13] = sh34;
    row[14] = sh35;
    row[15] = sh36;

    __syncthreads();

    // ---- coalesced writeout: TILE*16 floats = TILE*4 float4 ----
    const int valid_f4 = nvalid * 4;
    f32x4* otile = reinterpret_cast<f32x4*>(out + (long long)e0 * 16);

#pragma unroll
    for (int j = 0; j < 4; ++j) {
        int f = t + TILE * j;
        if (f < valid_f4) {
            int ee = f >> 2;
            int q  = f & 3;
            const float* r = &so[ee * PAD + q * 4];
            f32x4 v = { r[0], r[1], r[2], r[3] };
            __builtin_nontemporal_store(v, &otile[f]);
        }
    }
}

extern "C" void kernel_launch(void* const* d_in, const int* in_sizes, int n_in,
                              void* d_out, int out_size, void* d_ws, size_t ws_size,
                              hipStream_t stream) {
    const float* ev = (const float*)d_in[0];
    float* out = (float*)d_out;
    int n = in_sizes[0] / 3;

    int grid = (n + TILE - 1) / TILE;  // 12500 for N=3.2M
    sh_lmax3_kernel<<<grid, TILE, 0, stream>>>(ev, out, n);
}

// Round 5
// 39.875 us; speedup vs baseline: 1.1235x; 1.1235x over previous
//
#include <hip/hip_runtime.h>
#include <math.h>

// SH lmax=3 with normalization. f32 (N,3) -> f32 (N,16).
// One thread per output float4: no LDS, no barriers, fully coalesced stores.
// 4 threads share an edge (redundant compute is ~free at 5% VALUBusy;
// redundant loads merge in L1 — HBM read bytes unchanged).

typedef float f32x4 __attribute__((ext_vector_type(4)));

__global__ __launch_bounds__(256) void sh_lmax3_kernel(
    const float* __restrict__ ev, float* __restrict__ out, int n) {

    const float sqrt3  = 1.7320508075688772f;
    const float sqrt5  = 2.2360679774997896f;
    const float sqrt15 = 3.8729833462074170f;
    const float c30    = 1.0801234497346435f;  // sqrt(42)/6
    const float c31    = 2.6457513110645907f;  // sqrt(7)
    const float c32    = 1.6201851746019651f;  // sqrt(168)/8
    const float c33    = 1.3228756555322954f;  // 0.5*sqrt(7)

    int f = blockIdx.x * blockDim.x + threadIdx.x;  // output float4 index
    if (f >= n * 4) return;

    int e    = f >> 2;   // edge index
    int quad = f & 3;    // which float4 of the 16-float row

    float x = ev[3 * e + 0];
    float y = ev[3 * e + 1];
    float z = ev[3 * e + 2];

    float s  = x * x + y * y + z * z;
    float rn = 1.0f / fmaxf(sqrtf(s), 1e-12f);
    x *= rn; y *= rn; z *= rn;

    float y2   = y * y;
    float x2z2 = x * x + z * z;

    float sh10 = sqrt3 * x;
    float sh11 = sqrt3 * y;
    float sh12 = sqrt3 * z;

    float sh20 = sqrt15 * x * z;
    float sh21 = sqrt15 * x * y;
    float sh22 = sqrt5 * (y2 - 0.5f * x2z2);
    float sh23 = sqrt15 * y * z;
    float sh24 = 0.5f * sqrt15 * (z * z - x * x);

    float sh30 = c30 * (sh20 * z + sh24 * x);
    float sh31 = c31 * sh20 * y;
    float sh32 = c32 * (4.0f * y2 - x2z2) * x;
    float sh33 = c33 * y * (2.0f * y2 - 3.0f * x2z2);
    float sh34 = c32 * z * (4.0f * y2 - x2z2);
    float sh35 = c31 * sh24 * y;
    float sh36 = c30 * (sh24 * z - sh20 * x);

    // Select this thread's quad via cndmask chains (no divergent stores).
    f32x4 v;
    v.x = quad == 0 ? 1.0f : quad == 1 ? sh20 : quad == 2 ? sh24 : sh33;
    v.y = quad == 0 ? sh10 : quad == 1 ? sh21 : quad == 2 ? sh30 : sh34;
    v.z = quad == 0 ? sh11 : quad == 1 ? sh22 : quad == 2 ? sh31 : sh35;
    v.w = quad == 0 ? sh12 : quad == 1 ? sh23 : quad == 2 ? sh32 : sh36;

    reinterpret_cast<f32x4*>(out)[f] = v;
}

extern "C" void kernel_launch(void* const* d_in, const int* in_sizes, int n_in,
                              void* d_out, int out_size, void* d_ws, size_t ws_size,
                              hipStream_t stream) {
    const float* ev = (const float*)d_in[0];
    float* out = (float*)d_out;
    int n = in_sizes[0] / 3;

    long long nf4 = (long long)n * 4;               // 12.8M output float4s
    int grid = (int)((nf4 + 255) / 256);            // 50000 blocks
    sh_lmax3_kernel<<<grid, 256, 0, stream>>>(ev, out, n);
}

// Round 6
// 38.372 us; speedup vs baseline: 1.1675x; 1.0392x over previous
//
#include <hip/hip_runtime.h>
#include <math.h>

// SH lmax=3 with normalization. f32 (N,3) -> f32 (N,16).
// One thread per output float4: no LDS, no barriers, fully coalesced stores.
// R6: clean A/B vs R5 — nontemporal STORES only (output written once, never
// read; stream past L2 to keep it for the input read stream).

typedef float f32x4 __attribute__((ext_vector_type(4)));

__global__ __launch_bounds__(256) void sh_lmax3_kernel(
    const float* __restrict__ ev, float* __restrict__ out, int n) {

    const float sqrt3  = 1.7320508075688772f;
    const float sqrt5  = 2.2360679774997896f;
    const float sqrt15 = 3.8729833462074170f;
    const float c30    = 1.0801234497346435f;  // sqrt(42)/6
    const float c31    = 2.6457513110645907f;  // sqrt(7)
    const float c32    = 1.6201851746019651f;  // sqrt(168)/8
    const float c33    = 1.3228756555322954f;  // 0.5*sqrt(7)

    int f = blockIdx.x * blockDim.x + threadIdx.x;  // output float4 index
    if (f >= n * 4) return;

    int e    = f >> 2;   // edge index
    int quad = f & 3;    // which float4 of the 16-float row

    float x = ev[3 * e + 0];
    float y = ev[3 * e + 1];
    float z = ev[3 * e + 2];

    float s  = x * x + y * y + z * z;
    float rn = 1.0f / fmaxf(sqrtf(s), 1e-12f);
    x *= rn; y *= rn; z *= rn;

    float y2   = y * y;
    float x2z2 = x * x + z * z;

    float sh10 = sqrt3 * x;
    float sh11 = sqrt3 * y;
    float sh12 = sqrt3 * z;

    float sh20 = sqrt15 * x * z;
    float sh21 = sqrt15 * x * y;
    float sh22 = sqrt5 * (y2 - 0.5f * x2z2);
    float sh23 = sqrt15 * y * z;
    float sh24 = 0.5f * sqrt15 * (z * z - x * x);

    float sh30 = c30 * (sh20 * z + sh24 * x);
    float sh31 = c31 * sh20 * y;
    float sh32 = c32 * (4.0f * y2 - x2z2) * x;
    float sh33 = c33 * y * (2.0f * y2 - 3.0f * x2z2);
    float sh34 = c32 * z * (4.0f * y2 - x2z2);
    float sh35 = c31 * sh24 * y;
    float sh36 = c30 * (sh24 * z - sh20 * x);

    // Select this thread's quad via cndmask chains (no divergent stores).
    f32x4 v;
    v.x = quad == 0 ? 1.0f : quad == 1 ? sh20 : quad == 2 ? sh24 : sh33;
    v.y = quad == 0 ? sh10 : quad == 1 ? sh21 : quad == 2 ? sh30 : sh34;
    v.z = quad == 0 ? sh11 : quad == 1 ? sh22 : quad == 2 ? sh31 : sh35;
    v.w = quad == 0 ? sh12 : quad == 1 ? sh23 : quad == 2 ? sh32 : sh36;

    __builtin_nontemporal_store(v, &reinterpret_cast<f32x4*>(out)[f]);
}

extern "C" void kernel_launch(void* const* d_in, const int* in_sizes, int n_in,
                              void* d_out, int out_size, void* d_ws, size_t ws_size,
                              hipStream_t stream) {
    const float* ev = (const float*)d_in[0];
    float* out = (float*)d_out;
    int n = in_sizes[0] / 3;

    long long nf4 = (long long)n * 4;               // 12.8M output float4s
    int grid = (int)((nf4 + 255) / 256);            // 50000 blocks
    sh_lmax3_kernel<<<grid, 256, 0, stream>>>(ev, out, n);
}